// Round 2
// baseline (572.608 us; speedup 1.0000x reference)
//
#include <hip/hip_runtime.h>
#include <hip/hip_bf16.h>
#include <stdint.h>

#define NBATCH 512
#define FDIM   512   // graph_feat_size
#define NATOM  128   // N
#define KDIM   256   // attention K
#define NT     16    // f-tiles of 32

// LDS tile strides (bf16 elements). 40*2B = 80 B row stride:
//  - 16B alignment for ds_read_b128 fragments
//  - fragment reads only 2-way bank-aliased (free, m136)
#define VS_STRIDE 40
#define WS_STRIDE 40

typedef __attribute__((ext_vector_type(8))) __bf16         bf16x8;
typedef __attribute__((ext_vector_type(8))) unsigned short ushort8;
typedef __attribute__((ext_vector_type(4))) unsigned short ushort4v;
typedef __attribute__((ext_vector_type(4))) float          f32x4;

__device__ __forceinline__ float fast_tanh(float x) {
    float e = __expf(2.0f * x);
    return 1.0f - 2.0f / (e + 1.0f);
}

__device__ __forceinline__ unsigned short bf16_rne(float f) {
    unsigned int u = __float_as_uint(f);
    u += 0x7FFFu + ((u >> 16) & 1u);   // round-to-nearest-even
    return (unsigned short)(u >> 16);
}

// ---- pre-kernel: W_v, W_q f32 [256x512] -> bf16 in d_ws ----
__global__ __launch_bounds__(512)
void wconv_kernel(const float* __restrict__ Wv, const float* __restrict__ Wq,
                  unsigned short* __restrict__ out) {
    int i = blockIdx.x * 512 + threadIdx.x;          // 0..65535, 4 elements each
    const float* src = (i < 32768) ? Wv : Wq;
    int j = (i & 32767) * 4;
    float4 v = *(const float4*)(src + j);
    ushort4v o;
    o[0] = bf16_rne(v.x); o[1] = bf16_rne(v.y);
    o[2] = bf16_rne(v.z); o[3] = bf16_rne(v.w);
    *(ushort4v*)(out + (size_t)i * 4) = o;
}

__global__ __launch_bounds__(512, 4)
void coattn_kernel(const float* __restrict__ V_n, const float* __restrict__ Q_n,
                   const float* __restrict__ W_m, const float* __restrict__ W_h,
                   const unsigned short* __restrict__ Wv_bf,
                   const unsigned short* __restrict__ Wq_bf,
                   float* __restrict__ out)
{
    __shared__ unsigned short Ws[2][KDIM * WS_STRIDE];    // 2 x 20480 B
    __shared__ unsigned short VsT[2][NATOM * VS_STRIDE];  // 2 x 10240 B
    __shared__ float rsV[FDIM];
    __shared__ float rsQ[FDIM];
    __shared__ float m0s[FDIM];
    __shared__ float cgate[KDIM];
    __shared__ float s_lds[NATOM];
    __shared__ float alpha_lds[NATOM];

    const int b    = blockIdx.x;
    const int t    = threadIdx.x;
    const int lane = t & 63;
    const int wid  = t >> 6;      // 0..7
    const int wr   = wid >> 1;    // 0..3 : k-block of 64
    const int wc   = wid & 1;     // 0..1 : n-block of 64
    const int l15  = lane & 15;
    const int lg   = lane >> 4;   // 0..3

    const float* Vb = V_n + (size_t)b * FDIM * NATOM;
    const float* Qb = Q_n + (size_t)b * FDIM * NATOM;

    f32x4 accV[4][4], accQ[4][4];
    {
        f32x4 z = {0.f, 0.f, 0.f, 0.f};
        #pragma unroll
        for (int i = 0; i < 4; ++i)
            #pragma unroll
            for (int j = 0; j < 4; ++j) { accV[i][j] = z; accQ[i][j] = z; }
    }

    // ---- streamed GEMM, double-buffered (LDS + regs), one barrier/iter ----
    auto stream_gemm = [&](const float* src, const unsigned short* Wbf,
                           float* rowsum, f32x4 (&acc)[4][4]) {
        const int fr   = t >> 4;   // 0..31 : f-row within tile
        const int m    = t & 15;
        const int kw   = t >> 1;   // 0..255
        const int part = t & 1;

        float   vv[2][8];
        ushort8 wreg[2][2];

        auto issue_loads = [&](int s, int buf) {
            const float* srow = src + (size_t)(s * 32 + fr) * NATOM + m;
            #pragma unroll
            for (int i = 0; i < 8; ++i) vv[buf][i] = srow[16 * i];
            const ushort8* wrow =
                (const ushort8*)(Wbf + (size_t)kw * FDIM + s * 32 + part * 16);
            wreg[buf][0] = wrow[0];
            wreg[buf][1] = wrow[1];
        };

        auto write_lds = [&](int s, int buf) {
            float rs = 0.f;
            #pragma unroll
            for (int i = 0; i < 8; ++i) rs += vv[buf][i];
            rs += __shfl_xor(rs, 1);
            rs += __shfl_xor(rs, 2);
            rs += __shfl_xor(rs, 4);
            rs += __shfl_xor(rs, 8);
            if (m == 0) rowsum[s * 32 + fr] = rs;
            #pragma unroll
            for (int i = 0; i < 8; ++i)
                VsT[buf][(m + 16 * i) * VS_STRIDE + fr] = bf16_rne(vv[buf][i]);
            *(ushort8*)&Ws[buf][kw * WS_STRIDE + part * 16]     = wreg[buf][0];
            *(ushort8*)&Ws[buf][kw * WS_STRIDE + part * 16 + 8] = wreg[buf][1];
        };

        issue_loads(0, 0);
        write_lds(0, 0);
        issue_loads(1, 1);
        __syncthreads();

        #pragma unroll
        for (int s = 0; s < NT; ++s) {
            const int cur = s & 1;
            bf16x8 af[4], bfr[4];
            #pragma unroll
            for (int mi = 0; mi < 4; ++mi)
                af[mi] = __builtin_bit_cast(bf16x8,
                    *(const ushort8*)&Ws[cur][(wr * 64 + mi * 16 + l15) * WS_STRIDE + lg * 8]);
            #pragma unroll
            for (int ni = 0; ni < 4; ++ni)
                bfr[ni] = __builtin_bit_cast(bf16x8,
                    *(const ushort8*)&VsT[cur][(wc * 64 + ni * 16 + l15) * VS_STRIDE + lg * 8]);

            if (s + 2 < NT) issue_loads(s + 2, cur);       // regs[cur] free again
            if (s + 1 < NT) write_lds(s + 1, cur ^ 1);     // fill other LDS buffer

            #pragma unroll
            for (int mi = 0; mi < 4; ++mi)
                #pragma unroll
                for (int ni = 0; ni < 4; ++ni)
                    acc[mi][ni] = __builtin_amdgcn_mfma_f32_16x16x32_bf16(
                        af[mi], bfr[ni], acc[mi][ni], 0, 0, 0);
            __syncthreads();
        }
    };

    stream_gemm(Vb, Wv_bf, rsV, accV);
    stream_gemm(Qb, Wq_bf, rsQ, accQ);

    __syncthreads();
    m0s[t] = fast_tanh(rsV[t] * 0.015625f) * fast_tanh(rsQ[t] * 0.015625f);
    __syncthreads();

    // ---- gate GEMV: cgate[k] = tanh(W_m[k,:] . M0) * W_h[k] ----
    {
        const float4* m04 = (const float4*)m0s;
        float4 mb0 = m04[2 * lane], mb1 = m04[2 * lane + 1];
        for (int kk = wid; kk < KDIM; kk += 8) {
            const float4* wm4 = (const float4*)(W_m + (size_t)kk * FDIM);
            float4 a0 = wm4[2 * lane], a1 = wm4[2 * lane + 1];
            float sum = a0.x * mb0.x + a0.y * mb0.y + a0.z * mb0.z + a0.w * mb0.w
                      + a1.x * mb1.x + a1.y * mb1.y + a1.z * mb1.z + a1.w * mb1.w;
            #pragma unroll
            for (int o = 1; o < 64; o <<= 1) sum += __shfl_xor(sum, o);
            if (lane == 0) cgate[kk] = fast_tanh(sum) * W_h[kk];
        }
    }
    __syncthreads();

    // ---- per input: s[n] = sum_k cgate[k]*tanh(G[k,n]); softmax; weighted sum ----
    auto finish = [&](const f32x4 (&acc)[4][4], const float* src,
                      float* ovec, float* oalpha) {
        if (t < NATOM) s_lds[t] = 0.f;
        __syncthreads();
        float sp[4] = {0.f, 0.f, 0.f, 0.f};
        #pragma unroll
        for (int mi = 0; mi < 4; ++mi) {
            #pragma unroll
            for (int j = 0; j < 4; ++j) {
                const float c = cgate[wr * 64 + mi * 16 + lg * 4 + j];
                #pragma unroll
                for (int ni = 0; ni < 4; ++ni)
                    sp[ni] += c * fast_tanh(acc[mi][ni][j]);
            }
        }
        #pragma unroll
        for (int ni = 0; ni < 4; ++ni) {
            sp[ni] += __shfl_xor(sp[ni], 16);
            sp[ni] += __shfl_xor(sp[ni], 32);
        }
        if (lg == 0) {
            #pragma unroll
            for (int ni = 0; ni < 4; ++ni)
                atomicAdd(&s_lds[wc * 64 + ni * 16 + l15], sp[ni]);
        }
        __syncthreads();

        if (wid == 0) {   // softmax over 128 by wave 0
            float a  = s_lds[lane];
            float c2 = s_lds[64 + lane];
            float mx = fmaxf(a, c2);
            #pragma unroll
            for (int o = 1; o < 64; o <<= 1) mx = fmaxf(mx, __shfl_xor(mx, o));
            float ea = __expf(a - mx), eb = __expf(c2 - mx);
            float ssum = ea + eb;
            #pragma unroll
            for (int o = 1; o < 64; o <<= 1) ssum += __shfl_xor(ssum, o);
            float inv = 1.0f / ssum;
            ea *= inv; eb *= inv;
            alpha_lds[lane]      = ea;
            alpha_lds[64 + lane] = eb;
            oalpha[b * NATOM + lane]      = ea;
            oalpha[b * NATOM + 64 + lane] = eb;
        }
        __syncthreads();

        float al0 = alpha_lds[2 * lane], al1 = alpha_lds[2 * lane + 1];
        for (int r = 0; r < FDIM / 8; ++r) {
            const int f = r * 8 + wid;
            const float2 v2 = *(const float2*)(src + (size_t)f * NATOM + 2 * lane);
            float sacc = v2.x * al0 + v2.y * al1;
            #pragma unroll
            for (int o = 1; o < 64; o <<= 1) sacc += __shfl_xor(sacc, o);
            if (lane == 0) ovec[b * FDIM + f] = sacc;
        }
    };

    finish(accV, Vb, out,                 out + 2 * NBATCH * FDIM);
    __syncthreads();
    finish(accQ, Qb, out + NBATCH * FDIM, out + 2 * NBATCH * FDIM + NBATCH * NATOM);
}

extern "C" void kernel_launch(void* const* d_in, const int* in_sizes, int n_in,
                              void* d_out, int out_size, void* d_ws, size_t ws_size,
                              hipStream_t stream) {
    (void)in_sizes; (void)n_in; (void)out_size; (void)ws_size;
    const float* V_n = (const float*)d_in[0];
    const float* Q_n = (const float*)d_in[1];
    const float* W_m = (const float*)d_in[2];
    const float* W_v = (const float*)d_in[3];
    const float* W_q = (const float*)d_in[4];
    const float* W_h = (const float*)d_in[5];
    float* out = (float*)d_out;

    unsigned short* Wv_bf = (unsigned short*)d_ws;          // 256 KB
    unsigned short* Wq_bf = Wv_bf + KDIM * FDIM;            // 256 KB

    hipLaunchKernelGGL(wconv_kernel, dim3(128), dim3(512), 0, stream,
                       W_v, W_q, Wv_bf);
    hipLaunchKernelGGL(coattn_kernel, dim3(NBATCH), dim3(512), 0, stream,
                       V_n, Q_n, W_m, W_h, Wv_bf, Wq_bf, out);
}

// Round 3
// 374.029 us; speedup vs baseline: 1.5309x; 1.5309x over previous
//
#include <hip/hip_runtime.h>
#include <hip/hip_bf16.h>
#include <stdint.h>

#define NBATCH 512
#define FDIM   512   // graph_feat_size
#define NATOM  128   // N
#define KDIM   256   // attention K
#define NT     16    // f-tiles of 32

#define VS_STRIDE 40    // VsT row stride (ushorts): 80B rows, b128-aligned, floor-conflict reads
#define GV_STRIDE 132   // Gv row stride (ushorts): 264B rows, conflict-free b16 scatter/stream

typedef __attribute__((ext_vector_type(8))) __bf16         bf16x8;
typedef __attribute__((ext_vector_type(8))) unsigned short ushort8;
typedef __attribute__((ext_vector_type(4))) float          f32x4;

__device__ __forceinline__ float fast_tanh(float x) {
    float e = __expf(2.0f * x);
    return 1.0f - 2.0f / (e + 1.0f);
}
__device__ __forceinline__ unsigned short bf16_rne(float f) {
    unsigned int u = __float_as_uint(f);
    u += 0x7FFFu + ((u >> 16) & 1u);   // round-to-nearest-even
    return (unsigned short)(u >> 16);
}
__device__ __forceinline__ float bf16_to_f(unsigned short h) {
    return __uint_as_float(((unsigned int)h) << 16);
}
__device__ __forceinline__ bf16x8 ldfrag(const unsigned short* p) {
    return __builtin_bit_cast(bf16x8, *(const ushort8*)p);
}
__device__ __forceinline__ void glds16(const unsigned short* g, unsigned short* l) {
    __builtin_amdgcn_global_load_lds(
        (const __attribute__((address_space(1))) unsigned int*)g,
        (__attribute__((address_space(3))) unsigned int*)l, 16, 0, 0);
}

// ---- pre-kernel: W_v, W_q f32 [256x512] -> per-tile-contiguous bf16 image ----
// layout (ushort): [side][s][k][fo]  flat = ((side*16+s)*256 + k)*32 + fo
__global__ __launch_bounds__(256)
void wconv_kernel(const float* __restrict__ Wv, const float* __restrict__ Wq,
                  unsigned short* __restrict__ out) {
    int i = blockIdx.x * 256 + threadIdx.x;   // 32768 threads: side|s|k|c
    int c = i & 3, k = (i >> 2) & 255, s = (i >> 10) & 15, side = i >> 14;
    const float* W = side ? Wq : Wv;
    const float4* p = (const float4*)(W + (size_t)k * FDIM + s * 32 + c * 8);
    float4 a = p[0], b2 = p[1];
    ushort8 o;
    o[0] = bf16_rne(a.x);  o[1] = bf16_rne(a.y);
    o[2] = bf16_rne(a.z);  o[3] = bf16_rne(a.w);
    o[4] = bf16_rne(b2.x); o[5] = bf16_rne(b2.y);
    o[6] = bf16_rne(b2.z); o[7] = bf16_rne(b2.w);
    *(ushort8*)(out + (size_t)i * 8) = o;
}

__global__ __launch_bounds__(1024)
void coattn_kernel(const float* __restrict__ V_n, const float* __restrict__ Q_n,
                   const float* __restrict__ W_m, const float* __restrict__ W_h,
                   const unsigned short* __restrict__ Wt,
                   float* __restrict__ out)
{
    __shared__ unsigned short Ws[2][KDIM * 32];        // 32768 B (glds dest, linear)
    __shared__ unsigned short VsT[2][NATOM * VS_STRIDE]; // 20480 B
    __shared__ unsigned short Gv[KDIM * GV_STRIDE];    // 67584 B : tanh(W_v@V) bf16
    __shared__ float rsV[FDIM], rsQ[FDIM], m0s[FDIM];
    __shared__ float cgate[KDIM];
    __shared__ float sV[NATOM], sQ[NATOM], alV[NATOM], alQ[NATOM];

    const int b    = blockIdx.x;
    const int t    = threadIdx.x;
    const int lane = t & 63;
    const int wid  = t >> 6;      // 0..15
    const int wr   = wid >> 1;    // 0..7 : k-block of 32
    const int wc   = wid & 1;     // 0..1 : n-block of 64
    const int l15  = lane & 15;
    const int lg   = lane >> 4;   // 0..3
    const int fr   = t >> 5;      // 0..31 : f-row in staging
    const int m    = t & 31;      // n-coarse in staging

    const float* Vb = V_n + (size_t)b * FDIM * NATOM;
    const float* Qb = Q_n + (size_t)b * FDIM * NATOM;

    f32x4 acc[2][4];

    const int aoff = (wr * 32 + l15) * 32 + lg * 8;
    const int boff = (wc * 64 + l15) * VS_STRIDE + lg * 8;

    auto stream_gemm = [&](const float* src, const unsigned short* Wside,
                           float* rowsum) {
        {
            f32x4 z = {0.f, 0.f, 0.f, 0.f};
            #pragma unroll
            for (int i = 0; i < 2; ++i)
                #pragma unroll
                for (int j = 0; j < 4; ++j) acc[i][j] = z;
        }
        float vv[2][4];
        auto vload = [&](int s, int buf) {
            const float* p = src + (size_t)(s * 32 + fr) * NATOM + m;
            #pragma unroll
            for (int i = 0; i < 4; ++i) vv[buf][i] = p[32 * i];
        };
        auto vstore = [&](int s, int buf) {
            float rs = vv[buf][0] + vv[buf][1] + vv[buf][2] + vv[buf][3];
            rs += __shfl_xor(rs, 1);
            rs += __shfl_xor(rs, 2);
            rs += __shfl_xor(rs, 4);
            rs += __shfl_xor(rs, 8);
            rs += __shfl_xor(rs, 16);
            if (m == 0) rowsum[s * 32 + fr] = rs;
            #pragma unroll
            for (int i = 0; i < 4; ++i)
                VsT[buf][(m + 32 * i) * VS_STRIDE + fr] = bf16_rne(vv[buf][i]);
        };
        auto wstage = [&](int s, int buf) {
            glds16(Wside + (size_t)s * 8192 + wid * 512 + lane * 8,
                   &Ws[buf][wid * 512]);
        };

        vload(0, 0);
        vstore(0, 0);
        wstage(0, 0);
        vload(1, 1);
        __syncthreads();

        #pragma unroll
        for (int s = 0; s < NT; ++s) {
            const int cur = s & 1;
            bf16x8 af[2], bfr[4];
            #pragma unroll
            for (int mi = 0; mi < 2; ++mi)
                af[mi] = ldfrag(&Ws[cur][aoff + mi * 512]);
            #pragma unroll
            for (int ni = 0; ni < 4; ++ni)
                bfr[ni] = ldfrag(&VsT[cur][boff + ni * 16 * VS_STRIDE]);

            if (s + 2 < NT) vload(s + 2, cur);
            if (s + 1 < NT) { vstore(s + 1, cur ^ 1); wstage(s + 1, cur ^ 1); }

            #pragma unroll
            for (int mi = 0; mi < 2; ++mi)
                #pragma unroll
                for (int ni = 0; ni < 4; ++ni)
                    acc[mi][ni] = __builtin_amdgcn_mfma_f32_16x16x32_bf16(
                        af[mi], bfr[ni], acc[mi][ni], 0, 0, 0);
            __syncthreads();
        }
    };

    // ---- V pass; spill tanh(Gv) to LDS; reuse acc for Q pass ----
    stream_gemm(Vb, Wt, rsV);

    #pragma unroll
    for (int mi = 0; mi < 2; ++mi)
        #pragma unroll
        for (int ni = 0; ni < 4; ++ni)
            #pragma unroll
            for (int j = 0; j < 4; ++j) {
                const int k = wr * 32 + mi * 16 + lg * 4 + j;
                const int n = wc * 64 + ni * 16 + l15;
                Gv[k * GV_STRIDE + n] = bf16_rne(fast_tanh(acc[mi][ni][j]));
            }

    stream_gemm(Qb, Wt + 16 * 8192, rsQ);

    __syncthreads();
    if (t < FDIM)
        m0s[t] = fast_tanh(rsV[t] * 0.015625f) * fast_tanh(rsQ[t] * 0.015625f);
    __syncthreads();

    // ---- gate GEMV: cgate[k] = tanh(W_m[k,:] . M0) * W_h[k] ----
    {
        const float4* m04 = (const float4*)m0s;
        float4 mb0 = m04[2 * lane], mb1 = m04[2 * lane + 1];
        #pragma unroll
        for (int kk = wid; kk < KDIM; kk += 16) {
            const float4* wm4 = (const float4*)(W_m + (size_t)kk * FDIM);
            float4 a0 = wm4[2 * lane], a1 = wm4[2 * lane + 1];
            float sum = a0.x*mb0.x + a0.y*mb0.y + a0.z*mb0.z + a0.w*mb0.w
                      + a1.x*mb1.x + a1.y*mb1.y + a1.z*mb1.z + a1.w*mb1.w;
            #pragma unroll
            for (int o = 1; o < 64; o <<= 1) sum += __shfl_xor(sum, o);
            if (lane == 0) cgate[kk] = fast_tanh(sum) * W_h[kk];
        }
    }
    if (t < NATOM) sV[t] = 0.f;
    else if (t < 2 * NATOM) sQ[t - NATOM] = 0.f;
    __syncthreads();

    // ---- sQ from live acc ----
    {
        float sp[4] = {0.f, 0.f, 0.f, 0.f};
        #pragma unroll
        for (int mi = 0; mi < 2; ++mi)
            #pragma unroll
            for (int j = 0; j < 4; ++j) {
                const float c = cgate[wr * 32 + mi * 16 + lg * 4 + j];
                #pragma unroll
                for (int ni = 0; ni < 4; ++ni)
                    sp[ni] += c * fast_tanh(acc[mi][ni][j]);
            }
        #pragma unroll
        for (int ni = 0; ni < 4; ++ni) {
            sp[ni] += __shfl_xor(sp[ni], 16);
            sp[ni] += __shfl_xor(sp[ni], 32);
        }
        if (lg == 0) {
            #pragma unroll
            for (int ni = 0; ni < 4; ++ni)
                atomicAdd(&sQ[wc * 64 + ni * 16 + l15], sp[ni]);
        }
    }
    // ---- sV from Gv (tanh already applied) ----
    {
        float s0 = 0.f, s1 = 0.f;
        #pragma unroll
        for (int kk = 0; kk < 16; ++kk) {
            const int k = wid * 16 + kk;
            const float c = cgate[k];
            s0 += c * bf16_to_f(Gv[k * GV_STRIDE + lane]);
            s1 += c * bf16_to_f(Gv[k * GV_STRIDE + 64 + lane]);
        }
        atomicAdd(&sV[lane], s0);
        atomicAdd(&sV[64 + lane], s1);
    }
    __syncthreads();

    // ---- softmax: wave0 -> V, wave1 -> Q ----
    if (wid < 2) {
        float* sarr = wid ? sQ : sV;
        float* aarr = wid ? alQ : alV;
        float* oal  = out + 2 * (size_t)NBATCH * FDIM
                    + (size_t)wid * NBATCH * NATOM + (size_t)b * NATOM;
        float a  = sarr[lane];
        float c2 = sarr[64 + lane];
        float mx = fmaxf(a, c2);
        #pragma unroll
        for (int o = 1; o < 64; o <<= 1) mx = fmaxf(mx, __shfl_xor(mx, o));
        float ea = __expf(a - mx), eb = __expf(c2 - mx);
        float ssum = ea + eb;
        #pragma unroll
        for (int o = 1; o < 64; o <<= 1) ssum += __shfl_xor(ssum, o);
        float inv = 1.0f / ssum;
        ea *= inv; eb *= inv;
        aarr[lane] = ea; aarr[64 + lane] = eb;
        oal[lane]  = ea; oal[64 + lane]  = eb;
    }
    __syncthreads();

    // ---- fused weighted sums (re-read V,Q — L2/L3 resident) ----
    {
        float av0 = alV[2 * lane], av1 = alV[2 * lane + 1];
        float aq0 = alQ[2 * lane], aq1 = alQ[2 * lane + 1];
        float* ovV = out + (size_t)b * FDIM;
        float* ovQ = out + (size_t)NBATCH * FDIM + (size_t)b * FDIM;
        #pragma unroll 4
        for (int r = 0; r < 32; ++r) {
            const int f = r * 16 + wid;
            const float2 v2 = *(const float2*)(Vb + (size_t)f * NATOM + 2 * lane);
            const float2 q2 = *(const float2*)(Qb + (size_t)f * NATOM + 2 * lane);
            float sv = v2.x * av0 + v2.y * av1;
            float sq = q2.x * aq0 + q2.y * aq1;
            #pragma unroll
            for (int o = 1; o < 64; o <<= 1) {
                sv += __shfl_xor(sv, o);
                sq += __shfl_xor(sq, o);
            }
            if (lane == 0) { ovV[f] = sv; ovQ[f] = sq; }
        }
    }
}

extern "C" void kernel_launch(void* const* d_in, const int* in_sizes, int n_in,
                              void* d_out, int out_size, void* d_ws, size_t ws_size,
                              hipStream_t stream) {
    (void)in_sizes; (void)n_in; (void)out_size; (void)ws_size;
    const float* V_n = (const float*)d_in[0];
    const float* Q_n = (const float*)d_in[1];
    const float* W_m = (const float*)d_in[2];
    const float* W_v = (const float*)d_in[3];
    const float* W_q = (const float*)d_in[4];
    const float* W_h = (const float*)d_in[5];
    float* out = (float*)d_out;

    unsigned short* Wt = (unsigned short*)d_ws;   // 512 KB tiled bf16 image

    hipLaunchKernelGGL(wconv_kernel, dim3(128), dim3(256), 0, stream,
                       W_v, W_q, Wt);
    hipLaunchKernelGGL(coattn_kernel, dim3(NBATCH), dim3(1024), 0, stream,
                       V_n, Q_n, W_m, W_h, Wt, out);
}